// Round 8
// baseline (547.965 us; speedup 1.0000x reference)
//
#include <hip/hip_runtime.h>

#define VOCAB  82
#define EMBED  256
#define HIDDEN 128
#define BATCH  256
#define SEQ    512
#define KX     (HIDDEN + EMBED)   // 384 columns in each gate weight
#define SEG    36                 // padded LDS segment stride (32 data + 4 pad floats)

// Gate order: g=0 -> f (W_f), g=1 -> o (W_o), g=2 -> c_tilde (W_c)
// Gv layout: [VOCAB][3][HIDDEN] = per-token x-part of each gate pre-activation.
__device__ __align__(16) float Gv_buf[VOCAB * 3 * HIDDEN];

__device__ __forceinline__ float fast_sigmoid(float x) {
    return 1.f / (1.f + __expf(-x));
}
__device__ __forceinline__ float fast_tanh(float x) {
    x = fminf(fmaxf(x, -15.f), 15.f);
    float e = __expf(2.f * x);
    return (e - 1.f) / (e + 1.f);
}
// Quad-wide sum via DPP quad_perm (pure VALU, no LDS pipe).
__device__ __forceinline__ float quad_sum(float x) {
    int y1 = __builtin_amdgcn_mov_dpp(__float_as_int(x), 0xB1, 0xF, 0xF, true);
    x = x + __int_as_float(y1);
    int y2 = __builtin_amdgcn_mov_dpp(__float_as_int(x), 0x4E, 0xF, 0xF, true);
    return x + __int_as_float(y2);   // all 4 lanes end with the identical sum
}
// Pin a value into a VGPR: an asm def is NOT rematerializable.
#define PIN(x) asm volatile("" : "+v"(x))

// Raw barrier: LDS-visibility sync WITHOUT the vmcnt(0) drain __syncthreads
// emits. Gate stores stay in flight across steps (HK pattern, m194-m201).
__device__ __forceinline__ void block_sync_lds() {
    asm volatile("s_waitcnt lgkmcnt(0)" ::: "memory");
    __builtin_amdgcn_s_barrier();
    __builtin_amdgcn_sched_barrier(0);
}

// Prologue: one block per (v,g); 128 threads = one output row each.
__global__ __launch_bounds__(128, 2)
void gv_prologue(const float* __restrict__ emb,
                 const float* __restrict__ Wf,
                 const float* __restrict__ Wc,
                 const float* __restrict__ Wo) {
    const int g = blockIdx.x % 3;
    const int v = blockIdx.x / 3;
    const int r = threadIdx.x;

    __shared__ __align__(16) float e_lds[EMBED];
    e_lds[r]       = emb[(size_t)v * EMBED + r];
    e_lds[r + 128] = emb[(size_t)v * EMBED + r + 128];
    __syncthreads();

    const float* Wg = (g == 0) ? Wf : (g == 1) ? Wo : Wc;
    const float4* wr = (const float4*)(Wg + (size_t)r * KX + HIDDEN);
    const float4* ev = (const float4*)e_lds;
    float a0 = 0.f, a1 = 0.f, a2 = 0.f, a3 = 0.f;
#pragma unroll
    for (int i = 0; i < EMBED / 4; ++i) {
        float4 w4 = wr[i];
        float4 e4 = ev[i];
        a0 += w4.x * e4.x;
        a1 += w4.y * e4.y;
        a2 += w4.z * e4.z;
        a3 += w4.w * e4.w;
    }
    Gv_buf[(size_t)v * 384 + g * 128 + r] = (a0 + a1) + (a2 + a3);
}

// Main recurrence: 256 blocks (1/CU) x 512 threads (8 waves, 2/SIMD).
// Thread = (r = tid>>2, q = tid&3): all 3 gates of row r, K-quarter q.
// amdgpu_waves_per_eu(2,2): 256-VGPR budget so the 96 weight floats stay
// register-resident (round 5/6: default budget was 64 -> everything spilled).
__global__ void __attribute__((amdgpu_flat_work_group_size(512, 512),
                               amdgpu_waves_per_eu(2, 2)))
lstm_main(const int* __restrict__ tokens,
          const float* __restrict__ Wf,
          const float* __restrict__ Wc,
          const float* __restrict__ Wo,
          const float* __restrict__ clfW,
          const float* __restrict__ clfb,
          float* __restrict__ out) {
    const int b   = blockIdx.x;
    const int tid = threadIdx.x;        // 0..511
    const int q   = tid & 3;            // K-quarter / gate-lane
    const int r   = tid >> 2;           // 0..127 output row

    __shared__ __align__(16) float hbuf[2][4 * SEG];
    __shared__ int tok[SEQ];

    float4 wf[8], wo[8], wc[8];
    {
        const float4* pf = (const float4*)(Wf + (size_t)r * KX + q * 32);
        const float4* po = (const float4*)(Wo + (size_t)r * KX + q * 32);
        const float4* pc = (const float4*)(Wc + (size_t)r * KX + q * 32);
#pragma unroll
        for (int i = 0; i < 8; ++i) { wf[i] = pf[i]; wo[i] = po[i]; wc[i] = pc[i]; }
#pragma unroll
        for (int i = 0; i < 8; ++i) {
            PIN(wf[i].x); PIN(wf[i].y); PIN(wf[i].z); PIN(wf[i].w);
            PIN(wo[i].x); PIN(wo[i].y); PIN(wo[i].z); PIN(wo[i].w);
            PIN(wc[i].x); PIN(wc[i].y); PIN(wc[i].z); PIN(wc[i].w);
        }
    }

    tok[tid] = tokens[(size_t)b * SEQ + tid];        // 512 threads, 512 tokens
    if (tid < HIDDEN) hbuf[0][(tid >> 5) * SEG + (tid & 31)] = 0.f;
    float c = 0.f;                                   // replicated per quad lane
    __syncthreads();                                 // once, outside the loop

    const size_t GATE0 = (size_t)BATCH * VOCAB;
    const size_t GSZ   = (size_t)SEQ * BATCH * HIDDEN;
    float* gout = out + GATE0 + (size_t)q * GSZ + (size_t)b * HIDDEN + r;

    for (int t = 0; t < SEQ; ++t) {
        const int p  = t & 1;
        const int tk = tok[t];
        const float gx = (q < 3) ? Gv_buf[tk * 384 + q * 128 + r] : 0.f;

        const float4* hv4 = (const float4*)&hbuf[p][q * SEG];
        float pf = 0.f, po = 0.f, pc = 0.f;
#pragma unroll
        for (int i = 0; i < 8; ++i) {
            float4 h4 = hv4[i];
            pf += wf[i].x * h4.x; pf += wf[i].y * h4.y;
            pf += wf[i].z * h4.z; pf += wf[i].w * h4.w;
            po += wo[i].x * h4.x; po += wo[i].y * h4.y;
            po += wo[i].z * h4.z; po += wo[i].w * h4.w;
            pc += wc[i].x * h4.x; pc += wc[i].y * h4.y;
            pc += wc[i].z * h4.z; pc += wc[i].w * h4.w;
        }
        pf += (q == 0) ? gx : 0.f;
        po += (q == 1) ? gx : 0.f;
        pc += (q == 2) ? gx : 0.f;

        const float pre_f = quad_sum(pf);
        const float pre_o = quad_sum(po);
        const float pre_c = quad_sum(pc);

        const float f  = fast_sigmoid(pre_f);
        const float o  = fast_sigmoid(pre_o);
        const float ct = fast_tanh(pre_c);
        c = f * c + (1.f - f) * ct;
        const float h = o * fast_tanh(c);

        if (q == 0) hbuf[1 - p][(r >> 5) * SEG + (r & 31)] = h;
        block_sync_lds();                // lgkmcnt(0)+s_barrier, NO vmcnt drain
        const float sval = (q == 0) ? f : (q == 1) ? o : ct;
        if (q < 3) gout[(size_t)t * (BATCH * HIDDEN)] = sval;
    }

    // Epilogue: logits[b][v] = h_T . clfW[v] + clfb[v]; h_T is in hbuf[0]
    if (tid < 4 * VOCAB) {
        const int v = tid >> 2;
        const float4* cw  = (const float4*)(clfW + (size_t)v * HIDDEN + q * 32);
        const float4* hv4 = (const float4*)&hbuf[0][q * SEG];
        float a = 0.f;
#pragma unroll
        for (int i = 0; i < 8; ++i) {
            float4 w4 = cw[i];
            float4 h4 = hv4[i];
            a += w4.x * h4.x + w4.y * h4.y + w4.z * h4.z + w4.w * h4.w;
        }
        a = quad_sum(a);
        if (q == 0) out[(size_t)b * VOCAB + v] = a + clfb[v];
    }
}

extern "C" void kernel_launch(void* const* d_in, const int* in_sizes, int n_in,
                              void* d_out, int out_size, void* d_ws, size_t ws_size,
                              hipStream_t stream) {
    const int*   tokens = (const int*)  d_in[0];
    const float* emb    = (const float*)d_in[1];
    const float* Wf     = (const float*)d_in[2];
    const float* Wc     = (const float*)d_in[3];
    const float* Wo     = (const float*)d_in[4];
    const float* clfW   = (const float*)d_in[5];
    const float* clfb   = (const float*)d_in[6];
    float*       out    = (float*)d_out;

    gv_prologue<<<3 * VOCAB, 128, 0, stream>>>(emb, Wf, Wc, Wo);
    lstm_main<<<BATCH, 512, 0, stream>>>(tokens, Wf, Wc, Wo, clfW, clfb, out);
}